// Round 14
// baseline (32.291 us; speedup 1.0000x reference)
//
#include <hip/hip_runtime.h>
#include <math.h>

#define NPTS 262144
#define B_KB 4.71238898038469f      /* 1.5*pi */
#define B_KB2 22.2066099025f        /* B_KB^2 */
#define PI_F 3.14159265358979f
#define INV_2PI 0.15915494309f      /* 1/(2*pi) */
#define TWO_PI_OVER_N 0.01227184630309f /* 2*pi/512 */
#define NCOL 520                    /* padded row stride: 512 + 8 dup cols */
#define S_SCALE 1.37438953472e11f   /* 2^37: grid rescale into f16 range */
#define INV_S   7.27595761418e-12f  /* 2^-37 */

typedef _Float16 half8v __attribute__((ext_vector_type(8)));

__device__ __forceinline__ float i0f_dev(float x) {
    float ax = fabsf(x);
    if (ax < 3.75f) {
        float t = ax / 3.75f; t *= t;
        return 1.0f + t*(3.5156229f + t*(3.0899424f + t*(1.2067492f +
               t*(0.2659732f + t*(0.0360768f + t*0.0045813f)))));
    } else {
        float t = 3.75f / ax;
        float p = 0.39894228f + t*(0.01328592f + t*(0.00225319f + t*(-0.00157565f +
                  t*(0.00916281f + t*(-0.02057706f + t*(0.02635537f +
                  t*(-0.01647633f + t*0.00392377f)))))));
        return expf(ax) * p / sqrtf(ax);
    }
}

// Kaiser-Bessel window via raw v_exp/v_rcp: sinh(B*a)/(pi*a), a=sqrt(16-t^2)
__device__ __forceinline__ float phi_win(float t) {
    float s = 16.0f - t * t;
    if (s <= 0.0f) return 0.0f;
    float a = sqrtf(s);
    float ez = __expf(B_KB * a);
    return (ez - __builtin_amdgcn_rcpf(ez)) * INV_2PI * __builtin_amdgcn_rcpf(a);
}

// ---- Fused deconvolution + row FFT (rows with nonzero spectrum only). ----
// S_SCALE folded so the f16 grid lands in normal range; (-1)^(i1+i2) folded
// so the FFT output needs no ifftshift.
__global__ void rowfft_build(const float* __restrict__ fr,
                             const float* __restrict__ fi,
                             float2* __restrict__ g) {
    __shared__ float2 buf[512];
    int r = blockIdx.x;
    int i1 = (r < 128) ? r : r + 256;
    int k1 = (r < 128) ? r : r - 256;
    int tid = threadIdx.x;                 // 256 threads
    float a1 = TWO_PI_OVER_N * (float)k1;
    float ph1 = i0f_dev(4.0f * sqrtf(B_KB2 - a1 * a1));

    int k2 = tid - 128;                    // [-128, 128)
    int i2 = k2 & 511;
    float a2 = TWO_PI_OVER_N * (float)k2;
    float ph2 = i0f_dev(4.0f * sqrtf(B_KB2 - a2 * a2));
    float inv = S_SCALE / (ph1 * ph2);
    if ((i1 + i2) & 1) inv = -inv;
    int fidx = (k1 + 128) * 256 + (k2 + 128);
    float2 v = make_float2(fr[fidx] * inv, fi[fidx] * inv);

    buf[tid] = make_float2(0.0f, 0.0f);
    buf[tid + 256] = make_float2(0.0f, 0.0f);
    __syncthreads();
    int ri = (int)(__brev((unsigned)i2) >> 23);   // 9-bit reversal
    buf[ri] = v;
    __syncthreads();

    #pragma unroll
    for (int s = 1; s <= 9; ++s) {
        int half = 1 << (s - 1);
        int pos = tid & (half - 1);
        int j1 = ((tid >> (s - 1)) << s) | pos;
        float ang = -PI_F * (float)pos / (float)half;
        float sw, cw;
        __sincosf(ang, &sw, &cw);
        float2 u = buf[j1];
        float2 w = buf[j1 + half];
        float wr = cw * w.x - sw * w.y;
        float wi = cw * w.y + sw * w.x;
        buf[j1]        = make_float2(u.x + wr, u.y + wi);
        buf[j1 + half] = make_float2(u.x - wr, u.y - wi);
        __syncthreads();
    }
    long base = (long)i1 * NCOL;
    for (int j = tid; j < 512; j += 256) g[base + j] = buf[j];
    if (tid < 8) g[base + 512 + tid] = buf[tid];   // duplicate cols for padding
}

// ---- Column FFT over the 256 nonzero rows only; REAL part to f32 grid. ----
__global__ void colfft_real(const float2* __restrict__ g,
                            float* __restrict__ gre) {
    __shared__ float2 buf[512];
    int c = blockIdx.x;                    // 0..519
    int tid = threadIdx.x;                 // 256 threads
    buf[tid] = make_float2(0.0f, 0.0f);
    buf[tid + 256] = make_float2(0.0f, 0.0f);
    __syncthreads();
    int r = (tid < 128) ? tid : tid + 256;           // nonzero rows
    int rr = (int)(__brev((unsigned)r) >> 23);       // 9-bit reversal
    buf[rr] = g[(long)r * NCOL + c];
    __syncthreads();
    #pragma unroll
    for (int s = 1; s <= 9; ++s) {
        int half = 1 << (s - 1);
        int pos = tid & (half - 1);
        int j1 = ((tid >> (s - 1)) << s) | pos;
        float ang = -PI_F * (float)pos / (float)half;
        float sw, cw;
        __sincosf(ang, &sw, &cw);
        float2 u = buf[j1];
        float2 w = buf[j1 + half];
        float wr = cw * w.x - sw * w.y;
        float wi = cw * w.y + sw * w.x;
        buf[j1]        = make_float2(u.x + wr, u.y + wi);
        buf[j1 + half] = make_float2(u.x - wr, u.y - wi);
        __syncthreads();
    }
    for (int j = tid; j < 512; j += 256) gre[(long)j * NCOL + c] = buf[j].x;
}

// ---- Build 8 oct-row-interleaved f16 copies:
// og[s][ro][c][r] = (f16)gre[(8*ro+s+r) & 511][c], r=0..7 packed per column
// (16B). A point's 8x8 window (s = b1p&7) = ONE contiguous 128B segment. ----
__global__ void build_octs(const float* __restrict__ gre,
                           _Float16* __restrict__ og) {
    int u = blockIdx.x;                    // 0..511: s = u>>6, ro = u&63
    int s = u >> 6, ro = u & 63;
    int tid = threadIdx.x;                 // 256
    int r0 = 8 * ro + s;
    const float* gp0 = gre + (long)((r0    ) & 511) * NCOL;
    const float* gp1 = gre + (long)((r0 + 1) & 511) * NCOL;
    const float* gp2 = gre + (long)((r0 + 2) & 511) * NCOL;
    const float* gp3 = gre + (long)((r0 + 3) & 511) * NCOL;
    const float* gp4 = gre + (long)((r0 + 4) & 511) * NCOL;
    const float* gp5 = gre + (long)((r0 + 5) & 511) * NCOL;
    const float* gp6 = gre + (long)((r0 + 6) & 511) * NCOL;
    const float* gp7 = gre + (long)((r0 + 7) & 511) * NCOL;
    _Float16* outb = og + ((long)u * NCOL << 3);
    for (int c = tid; c < NCOL; c += 256) {
        half8v w;
        w[0] = (_Float16)gp0[c]; w[1] = (_Float16)gp1[c];
        w[2] = (_Float16)gp2[c]; w[3] = (_Float16)gp3[c];
        w[4] = (_Float16)gp4[c]; w[5] = (_Float16)gp5[c];
        w[6] = (_Float16)gp6[c]; w[7] = (_Float16)gp7[c];
        *reinterpret_cast<half8v*>(outb + ((long)c << 3)) = w;   // 16B coalesced
    }
}

// ---- Oct gather, 4 threads per point: thread q loads chunks {q, q+4}.
// Lanes 4k..4k+3 read consecutive 16B chunks -> each wave instruction
// presents only 16 distinct contiguous 64B regions to the TA. ----
__global__ __launch_bounds__(256)
void gather_oct4(const float2* __restrict__ x,
                 const _Float16* __restrict__ og,
                 float* __restrict__ out) {
    int t = blockIdx.x * 256 + threadIdx.x;   // 0 .. 4*NPTS-1
    int m = t >> 2;
    int q = t & 3;
    float2 xv = x[m];
    float v1 = xv.x * 512.0f;
    float v2 = xv.y * 512.0f;
    float c1 = ceilf(v1), c2 = ceilf(v2);
    int b1 = (int)c1 - 4, b2 = (int)c2 - 4;
    float f1 = c1 - v1, f2 = c2 - v2;

    int b1p = (b1 + 768) & 511;
    int b2p = (b2 + 768) & 511;
    int s  = b1p & 7;
    int ro = b1p >> 3;
    const _Float16* seg = og + (((long)(s * 64 + ro) * NCOL + b2p) << 3);

    half8v rv0 = *reinterpret_cast<const half8v*>(seg + (q << 3));        // col q
    half8v rv1 = *reinterpret_cast<const half8v*>(seg + ((q + 4) << 3));  // col q+4

    float phi1[8];
    #pragma unroll
    for (int r = 0; r < 8; ++r) phi1[r] = phi_win(4.0f - (float)r - f1);
    float p2a = phi_win(4.0f - (float)q - f2);
    float p2b = phi_win(4.0f - (float)(q + 4) - f2);

    float sa = 0.0f, sb = 0.0f;
    #pragma unroll
    for (int r = 0; r < 8; ++r) {
        sa += (float)rv0[r] * phi1[r];
        sb += (float)rv1[r] * phi1[r];
    }
    float acc = p2a * sa + p2b * sb;
    acc += __shfl_xor(acc, 1);
    acc += __shfl_xor(acc, 2);
    if (q == 0) out[m] = acc * INV_S;
}

// ================== fallback path (complex-capable, f32) ==================
__global__ void build_ghat(const float* __restrict__ fr,
                           const float* __restrict__ fi,
                           float2* __restrict__ g, int ldg) {
    int idx = blockIdx.x * 256 + threadIdx.x;
    int i1 = idx >> 9;
    int i2 = idx & 511;
    float2 val = make_float2(0.0f, 0.0f);
    int k1 = 0, k2 = 0;
    bool ok = true;
    if (i1 < 128) k1 = i1; else if (i1 >= 384) k1 = i1 - 512; else ok = false;
    if (ok) { if (i2 < 128) k2 = i2; else if (i2 >= 384) k2 = i2 - 512; else ok = false; }
    if (ok) {
        float a1 = TWO_PI_OVER_N * (float)k1;
        float a2 = TWO_PI_OVER_N * (float)k2;
        float ph1 = i0f_dev(4.0f * sqrtf(B_KB2 - a1*a1));
        float ph2 = i0f_dev(4.0f * sqrtf(B_KB2 - a2*a2));
        float inv = 1.0f / (ph1 * ph2);
        if ((i1 + i2) & 1) inv = -inv;
        int fidx = (k1 + 128) * 256 + (k2 + 128);
        val.x = fr[fidx] * inv;
        val.y = fi[fidx] * inv;
    }
    g[i1 * ldg + i2] = val;
}

__global__ void fft_lines(float2* __restrict__ g, int line_stride,
                          int elem_stride, int ndup) {
    __shared__ float2 buf[512];
    int line = blockIdx.x;
    int tid = threadIdx.x;
    long base = (long)line * line_stride;
    for (int j = tid; j < 512; j += 256) {
        int rj = (int)(__brev((unsigned)j) >> 23);
        buf[rj] = g[base + (long)j * elem_stride];
    }
    __syncthreads();
    #pragma unroll
    for (int s = 1; s <= 9; ++s) {
        int half = 1 << (s - 1);
        int pos = tid & (half - 1);
        int i1 = ((tid >> (s - 1)) << s) | pos;
        float ang = -PI_F * (float)pos / (float)half;
        float sw, cw;
        __sincosf(ang, &sw, &cw);
        float2 u = buf[i1];
        float2 v = buf[i1 + half];
        float wr = cw * v.x - sw * v.y;
        float wi = cw * v.y + sw * v.x;
        buf[i1]        = make_float2(u.x + wr, u.y + wi);
        buf[i1 + half] = make_float2(u.x - wr, u.y - wi);
        __syncthreads();
    }
    for (int j = tid; j < 512; j += 256) g[base + (long)j * elem_stride] = buf[j];
    for (int j = tid; j < ndup; j += 256) g[base + 512 + j] = buf[j];
}

template<int COMPLEX>
__global__ __launch_bounds__(256, 4)
void gather_pad(const float2* __restrict__ x,
                const float2* __restrict__ g,
                float* __restrict__ out) {
    int m = blockIdx.x * 256 + threadIdx.x;
    float2 xv = x[m];
    float v1 = xv.x * 512.0f;
    float v2 = xv.y * 512.0f;
    float c1 = ceilf(v1), c2 = ceilf(v2);
    int b1 = (int)c1 - 4, b2 = (int)c2 - 4;
    float f1 = c1 - v1, f2 = c2 - v2;

    float phi1[8], phi2[8];
    int rowb[8];
    #pragma unroll
    for (int w = 0; w < 8; ++w) {
        phi1[w] = phi_win(4.0f - (float)w - f1);
        phi2[w] = phi_win(4.0f - (float)w - f2);
        rowb[w] = ((b1 + w + 768) & 511) * NCOL;
    }
    int cb = (b2 + 768) & 511;

    float accx = 0.0f, accy = 0.0f;
    #pragma unroll
    for (int w1 = 0; w1 < 8; ++w1) {
        const float4* p = reinterpret_cast<const float4*>(g + rowb[w1] + cb);
        float4 va = p[0], vb = p[1], vc = p[2], vd = p[3];
        float p1 = phi1[w1];
        accx += p1 * (phi2[0]*va.x + phi2[1]*va.z + phi2[2]*vb.x + phi2[3]*vb.z +
                      phi2[4]*vc.x + phi2[5]*vc.z + phi2[6]*vd.x + phi2[7]*vd.z);
        if (COMPLEX)
            accy += p1 * (phi2[0]*va.y + phi2[1]*va.w + phi2[2]*vb.y + phi2[3]*vb.w +
                          phi2[4]*vc.y + phi2[5]*vc.w + phi2[6]*vd.y + phi2[7]*vd.w);
    }
    if (COMPLEX) ((float2*)out)[m] = make_float2(accx, accy);
    else out[m] = accx;
}

extern "C" void kernel_launch(void* const* d_in, const int* in_sizes, int n_in,
                              void* d_out, int out_size, void* d_ws, size_t ws_size,
                              hipStream_t stream) {
    const float* x  = (const float*)d_in[0];
    const float* fr = (const float*)d_in[1];
    const float* fi = (const float*)d_in[2];
    int cplx = (out_size >= 2 * NPTS) ? 1 : 0;

    size_t g_bytes   = (size_t)512 * NCOL * sizeof(float2);        // 2,129,920
    size_t gre_bytes = (size_t)512 * NCOL * sizeof(float);         // 1,064,960
    size_t og_bytes  = (size_t)512 * NCOL * 8 * sizeof(_Float16);  // 4,259,840
    char* ws = (char*)d_ws;
    float2*   g   = (float2*)ws;
    float*    gre = (float*)(ws + g_bytes);
    _Float16* og  = (_Float16*)(ws + g_bytes + gre_bytes);
    size_t need = g_bytes + gre_bytes + og_bytes;

    if (!cplx && ws_size >= need) {
        // Fast path: fused build+rowFFT, f32 colFFT, oct-interleave copy,
        // 4-threads-per-point gather with lane-quad-contiguous 64B reads.
        rowfft_build<<<256, 256, 0, stream>>>(fr, fi, g);
        colfft_real<<<NCOL, 256, 0, stream>>>(g, gre);
        build_octs<<<512, 256, 0, stream>>>(gre, og);
        gather_oct4<<<4096, 256, 0, stream>>>((const float2*)x, og, (float*)d_out);
    } else if (ws_size >= g_bytes) {
        build_ghat<<<1024, 256, 0, stream>>>(fr, fi, g, NCOL);
        fft_lines<<<512, 256, 0, stream>>>(g, NCOL, 1, 8);
        fft_lines<<<NCOL, 256, 0, stream>>>(g, 1, NCOL, 0);
        if (cplx)
            gather_pad<1><<<1024, 256, 0, stream>>>((const float2*)x, g, (float*)d_out);
        else
            gather_pad<0><<<1024, 256, 0, stream>>>((const float2*)x, g, (float*)d_out);
    } else {
        build_ghat<<<1024, 256, 0, stream>>>(fr, fi, g, 512);
        fft_lines<<<512, 256, 0, stream>>>(g, 512, 1, 0);
        fft_lines<<<512, 256, 0, stream>>>(g, 1, 512, 0);
        if (cplx)
            gather_pad<1><<<1024, 256, 0, stream>>>((const float2*)x, g, (float*)d_out);
        else
            gather_pad<0><<<1024, 256, 0, stream>>>((const float2*)x, g, (float*)d_out);
    }
}

// Round 15
// 26.224 us; speedup vs baseline: 1.2314x; 1.2314x over previous
//
#include <hip/hip_runtime.h>
#include <math.h>

#define NPTS 262144
#define B_KB 4.71238898038469f      /* 1.5*pi */
#define B_KB2 22.2066099025f        /* B_KB^2 */
#define PI_F 3.14159265358979f
#define INV_2PI 0.15915494309f      /* 1/(2*pi) */
#define TWO_PI_OVER_N 0.01227184630309f /* 2*pi/512 */
#define NCOL 520                    /* padded row stride: 512 + 8 dup cols */
#define S_SCALE 1.37438953472e11f   /* 2^37: grid rescale into f16 range */
#define INV_S   7.27595761418e-12f  /* 2^-37 */

typedef _Float16 half8v __attribute__((ext_vector_type(8)));
typedef _Float16 half4v __attribute__((ext_vector_type(4)));

__device__ __forceinline__ float i0f_dev(float x) {
    float ax = fabsf(x);
    if (ax < 3.75f) {
        float t = ax / 3.75f; t *= t;
        return 1.0f + t*(3.5156229f + t*(3.0899424f + t*(1.2067492f +
               t*(0.2659732f + t*(0.0360768f + t*0.0045813f)))));
    } else {
        float t = 3.75f / ax;
        float p = 0.39894228f + t*(0.01328592f + t*(0.00225319f + t*(-0.00157565f +
                  t*(0.00916281f + t*(-0.02057706f + t*(0.02635537f +
                  t*(-0.01647633f + t*0.00392377f)))))));
        return expf(ax) * p / sqrtf(ax);
    }
}

// Kaiser-Bessel window via raw v_exp/v_rcp: sinh(B*a)/(pi*a), a=sqrt(16-t^2)
__device__ __forceinline__ float phi_win(float t) {
    float s = 16.0f - t * t;
    if (s <= 0.0f) return 0.0f;
    float a = sqrtf(s);
    float ez = __expf(B_KB * a);
    return (ez - __builtin_amdgcn_rcpf(ez)) * INV_2PI * __builtin_amdgcn_rcpf(a);
}

// ---- Fused deconvolution + row FFT (rows with nonzero spectrum only). ----
// S_SCALE folded so the f16 grid lands in normal range; (-1)^(i1+i2) folded
// so the FFT output needs no ifftshift.
__global__ void rowfft_build(const float* __restrict__ fr,
                             const float* __restrict__ fi,
                             float2* __restrict__ g) {
    __shared__ float2 buf[512];
    int r = blockIdx.x;
    int i1 = (r < 128) ? r : r + 256;
    int k1 = (r < 128) ? r : r - 256;
    int tid = threadIdx.x;                 // 256 threads
    float a1 = TWO_PI_OVER_N * (float)k1;
    float ph1 = i0f_dev(4.0f * sqrtf(B_KB2 - a1 * a1));

    int k2 = tid - 128;                    // [-128, 128)
    int i2 = k2 & 511;
    float a2 = TWO_PI_OVER_N * (float)k2;
    float ph2 = i0f_dev(4.0f * sqrtf(B_KB2 - a2 * a2));
    float inv = S_SCALE / (ph1 * ph2);
    if ((i1 + i2) & 1) inv = -inv;
    int fidx = (k1 + 128) * 256 + (k2 + 128);
    float2 v = make_float2(fr[fidx] * inv, fi[fidx] * inv);

    buf[tid] = make_float2(0.0f, 0.0f);
    buf[tid + 256] = make_float2(0.0f, 0.0f);
    __syncthreads();
    int ri = (int)(__brev((unsigned)i2) >> 23);   // 9-bit reversal
    buf[ri] = v;
    __syncthreads();

    #pragma unroll
    for (int s = 1; s <= 9; ++s) {
        int half = 1 << (s - 1);
        int pos = tid & (half - 1);
        int j1 = ((tid >> (s - 1)) << s) | pos;
        float ang = -PI_F * (float)pos / (float)half;
        float sw, cw;
        __sincosf(ang, &sw, &cw);
        float2 u = buf[j1];
        float2 w = buf[j1 + half];
        float wr = cw * w.x - sw * w.y;
        float wi = cw * w.y + sw * w.x;
        buf[j1]        = make_float2(u.x + wr, u.y + wi);
        buf[j1 + half] = make_float2(u.x - wr, u.y - wi);
        __syncthreads();
    }
    long base = (long)i1 * NCOL;
    for (int j = tid; j < 512; j += 256) g[base + j] = buf[j];
    if (tid < 8) g[base + 512 + tid] = buf[tid];   // duplicate cols for padding
}

// ---- Column FFT (256 nonzero rows only) fused with quad-interleave emit:
// qg[s][rq][c] packs rows (4rq+s .. 4rq+s+3) mod 512 of column c as 4 f16
// (8B). Eliminates the gre round-trip and the separate build_quads pass. ----
__global__ void colfft_quads(const float2* __restrict__ g,
                             _Float16* __restrict__ qg) {
    __shared__ float2 buf[512];
    int c = blockIdx.x;                    // 0..519
    int tid = threadIdx.x;                 // 256 threads
    buf[tid] = make_float2(0.0f, 0.0f);
    buf[tid + 256] = make_float2(0.0f, 0.0f);
    __syncthreads();
    int r = (tid < 128) ? tid : tid + 256;           // nonzero rows
    int rr = (int)(__brev((unsigned)r) >> 23);       // 9-bit reversal
    buf[rr] = g[(long)r * NCOL + c];
    __syncthreads();
    #pragma unroll
    for (int s = 1; s <= 9; ++s) {
        int half = 1 << (s - 1);
        int pos = tid & (half - 1);
        int j1 = ((tid >> (s - 1)) << s) | pos;
        float ang = -PI_F * (float)pos / (float)half;
        float sw, cw;
        __sincosf(ang, &sw, &cw);
        float2 u = buf[j1];
        float2 w = buf[j1 + half];
        float wr = cw * w.x - sw * w.y;
        float wi = cw * w.y + sw * w.x;
        buf[j1]        = make_float2(u.x + wr, u.y + wi);
        buf[j1 + half] = make_float2(u.x - wr, u.y - wi);
        __syncthreads();
    }
    #pragma unroll
    for (int u0 = 0; u0 < 2; ++u0) {
        int u = tid + u0 * 256;            // 0..511: s = u>>7, rq = u&127
        int rq = u & 127;
        int s = u >> 7;
        int r0 = 4 * rq + s;
        half4v w;
        w[0] = (_Float16)buf[(r0    ) & 511].x;
        w[1] = (_Float16)buf[(r0 + 1) & 511].x;
        w[2] = (_Float16)buf[(r0 + 2) & 511].x;
        w[3] = (_Float16)buf[(r0 + 3) & 511].x;
        *reinterpret_cast<half4v*>(qg + (((long)u * NCOL + c) << 2)) = w;
    }
}

// ---- Quad gather: 2 threads per point; thread h loads quad rq0+h as
// 4 x dwordx4 (64B contiguous). phi2 split across the pair and exchanged
// via shfl_xor (8 phi_win/thread instead of 12). ----
__global__ __launch_bounds__(256)
void gather_quads(const float2* __restrict__ x,
                  const _Float16* __restrict__ qg,
                  float* __restrict__ out) {
    int t = blockIdx.x * 256 + threadIdx.x;   // 0 .. 2*NPTS-1
    int m = t >> 1;
    int h = t & 1;
    float2 xv = x[m];
    float v1 = xv.x * 512.0f;
    float v2 = xv.y * 512.0f;
    float c1 = ceilf(v1), c2 = ceilf(v2);
    int b1 = (int)c1 - 4, b2 = (int)c2 - 4;
    float f1 = c1 - v1, f2 = c2 - v2;

    int b1p = (b1 + 768) & 511;
    int b2p = (b2 + 768) & 511;
    int s  = b1p & 3;
    int rq = ((b1p >> 2) + h) & 127;
    const _Float16* base = qg + (((long)(s * 128 + rq) * NCOL + b2p) << 2);

    half8v rv[4];                           // 4 x 16B, contiguous 64B total
    #pragma unroll
    for (int li = 0; li < 4; ++li)
        rv[li] = *reinterpret_cast<const half8v*>(base + (li << 3));

    // my 4 window rows (rows 4h..4h+3 of the window)
    float phi1h[4];
    #pragma unroll
    for (int r = 0; r < 4; ++r)
        phi1h[r] = phi_win(4.0f - (float)(4 * h + r) - f1);
    // my 4 window cols (cols 4h..4h+3); partner's 4 via shfl
    float p2own[4], p2oth[4];
    #pragma unroll
    for (int r = 0; r < 4; ++r) {
        p2own[r] = phi_win(4.0f - (float)(4 * h + r) - f2);
        p2oth[r] = __shfl_xor(p2own[r], 1);
    }
    float ph2[8];
    #pragma unroll
    for (int j = 0; j < 8; ++j) {
        float a = p2own[j & 3], b = p2oth[j & 3];
        ph2[j] = ((j >> 2) == h) ? a : b;   // compile-time j, runtime select
    }

    float acc = 0.0f;
    #pragma unroll
    for (int li = 0; li < 4; ++li) {
        #pragma unroll
        for (int k = 0; k < 8; ++k) {
            int j = (li << 1) + (k >> 2);   // window col
            int r = k & 3;                  // row within quad
            acc += (float)rv[li][k] * (phi1h[r] * ph2[j]);
        }
    }
    acc += __shfl_xor(acc, 1);
    if (h == 0) out[m] = acc * INV_S;
}

// ================== fallback path (complex-capable, f32) ==================
__global__ void build_ghat(const float* __restrict__ fr,
                           const float* __restrict__ fi,
                           float2* __restrict__ g, int ldg) {
    int idx = blockIdx.x * 256 + threadIdx.x;
    int i1 = idx >> 9;
    int i2 = idx & 511;
    float2 val = make_float2(0.0f, 0.0f);
    int k1 = 0, k2 = 0;
    bool ok = true;
    if (i1 < 128) k1 = i1; else if (i1 >= 384) k1 = i1 - 512; else ok = false;
    if (ok) { if (i2 < 128) k2 = i2; else if (i2 >= 384) k2 = i2 - 512; else ok = false; }
    if (ok) {
        float a1 = TWO_PI_OVER_N * (float)k1;
        float a2 = TWO_PI_OVER_N * (float)k2;
        float ph1 = i0f_dev(4.0f * sqrtf(B_KB2 - a1*a1));
        float ph2 = i0f_dev(4.0f * sqrtf(B_KB2 - a2*a2));
        float inv = 1.0f / (ph1 * ph2);
        if ((i1 + i2) & 1) inv = -inv;
        int fidx = (k1 + 128) * 256 + (k2 + 128);
        val.x = fr[fidx] * inv;
        val.y = fi[fidx] * inv;
    }
    g[i1 * ldg + i2] = val;
}

__global__ void fft_lines(float2* __restrict__ g, int line_stride,
                          int elem_stride, int ndup) {
    __shared__ float2 buf[512];
    int line = blockIdx.x;
    int tid = threadIdx.x;
    long base = (long)line * line_stride;
    for (int j = tid; j < 512; j += 256) {
        int rj = (int)(__brev((unsigned)j) >> 23);
        buf[rj] = g[base + (long)j * elem_stride];
    }
    __syncthreads();
    #pragma unroll
    for (int s = 1; s <= 9; ++s) {
        int half = 1 << (s - 1);
        int pos = tid & (half - 1);
        int i1 = ((tid >> (s - 1)) << s) | pos;
        float ang = -PI_F * (float)pos / (float)half;
        float sw, cw;
        __sincosf(ang, &sw, &cw);
        float2 u = buf[i1];
        float2 v = buf[i1 + half];
        float wr = cw * v.x - sw * v.y;
        float wi = cw * v.y + sw * v.x;
        buf[i1]        = make_float2(u.x + wr, u.y + wi);
        buf[i1 + half] = make_float2(u.x - wr, u.y - wi);
        __syncthreads();
    }
    for (int j = tid; j < 512; j += 256) g[base + (long)j * elem_stride] = buf[j];
    for (int j = tid; j < ndup; j += 256) g[base + 512 + j] = buf[j];
}

template<int COMPLEX>
__global__ __launch_bounds__(256, 4)
void gather_pad(const float2* __restrict__ x,
                const float2* __restrict__ g,
                float* __restrict__ out) {
    int m = blockIdx.x * 256 + threadIdx.x;
    float2 xv = x[m];
    float v1 = xv.x * 512.0f;
    float v2 = xv.y * 512.0f;
    float c1 = ceilf(v1), c2 = ceilf(v2);
    int b1 = (int)c1 - 4, b2 = (int)c2 - 4;
    float f1 = c1 - v1, f2 = c2 - v2;

    float phi1[8], phi2[8];
    int rowb[8];
    #pragma unroll
    for (int w = 0; w < 8; ++w) {
        phi1[w] = phi_win(4.0f - (float)w - f1);
        phi2[w] = phi_win(4.0f - (float)w - f2);
        rowb[w] = ((b1 + w + 768) & 511) * NCOL;
    }
    int cb = (b2 + 768) & 511;

    float accx = 0.0f, accy = 0.0f;
    #pragma unroll
    for (int w1 = 0; w1 < 8; ++w1) {
        const float4* p = reinterpret_cast<const float4*>(g + rowb[w1] + cb);
        float4 va = p[0], vb = p[1], vc = p[2], vd = p[3];
        float p1 = phi1[w1];
        accx += p1 * (phi2[0]*va.x + phi2[1]*va.z + phi2[2]*vb.x + phi2[3]*vb.z +
                      phi2[4]*vc.x + phi2[5]*vc.z + phi2[6]*vd.x + phi2[7]*vd.z);
        if (COMPLEX)
            accy += p1 * (phi2[0]*va.y + phi2[1]*va.w + phi2[2]*vb.y + phi2[3]*vb.w +
                          phi2[4]*vc.y + phi2[5]*vc.w + phi2[6]*vd.y + phi2[7]*vd.w);
    }
    if (COMPLEX) ((float2*)out)[m] = make_float2(accx, accy);
    else out[m] = accx;
}

extern "C" void kernel_launch(void* const* d_in, const int* in_sizes, int n_in,
                              void* d_out, int out_size, void* d_ws, size_t ws_size,
                              hipStream_t stream) {
    const float* x  = (const float*)d_in[0];
    const float* fr = (const float*)d_in[1];
    const float* fi = (const float*)d_in[2];
    int cplx = (out_size >= 2 * NPTS) ? 1 : 0;

    size_t g_bytes  = (size_t)512 * NCOL * sizeof(float2);        // 2,129,920
    size_t qg_bytes = (size_t)512 * NCOL * 4 * sizeof(_Float16);  // 2,129,920
    char* ws = (char*)d_ws;
    float2*   g  = (float2*)ws;
    _Float16* qg = (_Float16*)(ws + g_bytes);
    size_t need = g_bytes + qg_bytes;

    if (!cplx && ws_size >= need) {
        // Fast path (3 kernels): fused build+rowFFT, colFFT fused with
        // quad-interleave emit, pair-split gather with phi sharing.
        rowfft_build<<<256, 256, 0, stream>>>(fr, fi, g);
        colfft_quads<<<NCOL, 256, 0, stream>>>(g, qg);
        gather_quads<<<2048, 256, 0, stream>>>((const float2*)x, qg, (float*)d_out);
    } else if (ws_size >= g_bytes) {
        build_ghat<<<1024, 256, 0, stream>>>(fr, fi, g, NCOL);
        fft_lines<<<512, 256, 0, stream>>>(g, NCOL, 1, 8);
        fft_lines<<<NCOL, 256, 0, stream>>>(g, 1, NCOL, 0);
        if (cplx)
            gather_pad<1><<<1024, 256, 0, stream>>>((const float2*)x, g, (float*)d_out);
        else
            gather_pad<0><<<1024, 256, 0, stream>>>((const float2*)x, g, (float*)d_out);
    } else {
        build_ghat<<<1024, 256, 0, stream>>>(fr, fi, g, 512);
        fft_lines<<<512, 256, 0, stream>>>(g, 512, 1, 0);
        fft_lines<<<512, 256, 0, stream>>>(g, 1, 512, 0);
        if (cplx)
            gather_pad<1><<<1024, 256, 0, stream>>>((const float2*)x, g, (float*)d_out);
        else
            gather_pad<0><<<1024, 256, 0, stream>>>((const float2*)x, g, (float*)d_out);
    }
}